// Round 5
// baseline (385.651 us; speedup 1.0000x reference)
//
#include <hip/hip_runtime.h>
#include <hip/hip_bf16.h>
#include <stdint.h>

#define B_  4
#define S_  2048
#define D_  1024
#define H_  16
#define HD_ 64

typedef __attribute__((ext_vector_type(4))) float f32x4;
typedef __attribute__((ext_vector_type(8))) short bf16x8;

typedef const unsigned int __attribute__((address_space(1)))* gas_ptr;
typedef unsigned int __attribute__((address_space(3)))* las_ptr;

__device__ __forceinline__ void async16(const void* g, void* l) {
  __builtin_amdgcn_global_load_lds((gas_ptr)g, (las_ptr)l, 16, 0, 0);
}

// ---------------------------------------------------------------------------
// x fp32 -> bf16
// ---------------------------------------------------------------------------
__global__ __launch_bounds__(256) void cvt_x(const float* __restrict__ in,
                                             __hip_bfloat16* __restrict__ out,
                                             int n) {
  const int i = (blockIdx.x * blockDim.x + threadIdx.x) * 4;
  if (i >= n) return;
  const float4 v = *(const float4*)(in + i);
  union { ushort4 u; __hip_bfloat16 h[4]; } o;
  o.h[0] = (__hip_bfloat16)v.x;
  o.h[1] = (__hip_bfloat16)v.y;
  o.h[2] = (__hip_bfloat16)v.z;
  o.h[3] = (__hip_bfloat16)v.w;
  *(ushort4*)(out + i) = o.u;
}

// ---------------------------------------------------------------------------
// mask int32 -> expanded bf16-AND masks (0xFFFF keep / 0x0000 drop), laid out
// exactly as flash_attn's packed-P pairs consume them:
//   u32 index = ((((b*2048+q)*32 + kt)*4 + quad)*8) + mt*2 + h
// ---------------------------------------------------------------------------
__global__ __launch_bounds__(256) void expand_mask(const int* __restrict__ mk,
                                                   uint2* __restrict__ xm) {
  const unsigned j = blockIdx.x * 256 + threadIdx.x;
  const int mt = j & 3, quad = (j >> 2) & 3, kt = (j >> 4) & 31;
  const int q = (j >> 9) & 2047, b = j >> 20;
  const size_t row = (size_t)b * 2048 + q;
  const int key = kt * 64 + mt * 16 + quad * 4;
  const int4 m = *(const int4*)(mk + row * 2048 + key);
  uint2 o;
  o.x = (m.x ? 0xFFFFu : 0u) | (m.y ? 0xFFFF0000u : 0u);
  o.y = (m.z ? 0xFFFFu : 0u) | (m.w ? 0xFFFF0000u : 0u);
  xm[j] = o;
}

// ---------------------------------------------------------------------------
// weights fp32 [K,N] -> bf16 transposed [N,K]
// ---------------------------------------------------------------------------
__global__ void transpose_w(const float* __restrict__ Wq,
                            const float* __restrict__ Wk,
                            const float* __restrict__ Wv,
                            const float* __restrict__ Wo,
                            __hip_bfloat16* __restrict__ Wt_qkv,
                            __hip_bfloat16* __restrict__ Wt_o) {
  __shared__ float t[32][33];
  const int z = blockIdx.z;
  const float* W = (z == 0) ? Wq : (z == 1) ? Wk : (z == 2) ? Wv : Wo;
  __hip_bfloat16* Wt = (z < 3) ? (Wt_qkv + (size_t)z * D_ * D_) : Wt_o;
  const int x = blockIdx.x * 32 + threadIdx.x;
  const int y = blockIdx.y * 32 + threadIdx.y;
  t[threadIdx.y][threadIdx.x] = W[(size_t)y * D_ + x];
  __syncthreads();
  const int xo = blockIdx.y * 32 + threadIdx.x;
  const int yo = blockIdx.x * 32 + threadIdx.y;
  Wt[(size_t)yo * D_ + xo] = (__hip_bfloat16)t[threadIdx.x][threadIdx.y];
}

// ---------------------------------------------------------------------------
// QKV GEMM: C[8192,3072] = X16 @ Wt_qkv^T + bias. Q cols scaled by
// 0.125*log2(e) (softmax scale folded into Q). Q,K -> QKo [8192][2048];
// V -> Vt [B*H*64][2048] (pre-transposed for flash A-operand use).
// ---------------------------------------------------------------------------
__global__ __launch_bounds__(256) void gemm_qkv(
    const __hip_bfloat16* __restrict__ A,
    const __hip_bfloat16* __restrict__ Bt,
    const float* __restrict__ bq,
    const float* __restrict__ bk,
    const float* __restrict__ bv,
    __hip_bfloat16* __restrict__ QKo,
    __hip_bfloat16* __restrict__ Vt) {
  __shared__ __hip_bfloat16 sA[128 * 32];
  __shared__ __hip_bfloat16 sB[128 * 32];
  const int K = 1024;
  const int tid  = threadIdx.x;
  const int wave = tid >> 6;
  const int lane = tid & 63;
  const int quad = lane >> 4;
  const int l16  = lane & 15;
  const int bm = blockIdx.y * 128;
  const int bn = blockIdx.x * 128;
  const int wm = (wave >> 1) * 64;
  const int wn = (wave & 1) * 64;

  const int r0 = wave * 2, r1 = wave * 2 + 1;
  const int lrow = lane >> 2;
  const int lcol = (lane & 3) * 8;

  const __hip_bfloat16* ga0 = A  + (size_t)(bm + r0 * 16 + lrow) * K + lcol;
  const __hip_bfloat16* ga1 = A  + (size_t)(bm + r1 * 16 + lrow) * K + lcol;
  const __hip_bfloat16* gb0 = Bt + (size_t)(bn + r0 * 16 + lrow) * K + lcol;
  const __hip_bfloat16* gb1 = Bt + (size_t)(bn + r1 * 16 + lrow) * K + lcol;
  char* la0 = (char*)sA + r0 * 1024;
  char* la1 = (char*)sA + r1 * 1024;
  char* lb0 = (char*)sB + r0 * 1024;
  char* lb1 = (char*)sB + r1 * 1024;

  const char* pa = (const char*)sA + (wm + l16) * 64 + quad * 16;
  const char* pb = (const char*)sB + (wn + l16) * 64 + quad * 16;

  f32x4 acc[4][4] = {};

  for (int k0 = 0; k0 < K; k0 += 32) {
    async16(ga0 + k0, la0);
    async16(ga1 + k0, la1);
    async16(gb0 + k0, lb0);
    async16(gb1 + k0, lb1);
    __syncthreads();
    bf16x8 af[4], bf[4];
#pragma unroll
    for (int mt = 0; mt < 4; ++mt) af[mt] = *(const bf16x8*)(pa + mt * 1024);
#pragma unroll
    for (int nt = 0; nt < 4; ++nt) bf[nt] = *(const bf16x8*)(pb + nt * 1024);
#pragma unroll
    for (int mt = 0; mt < 4; ++mt)
#pragma unroll
      for (int nt = 0; nt < 4; ++nt)
        acc[mt][nt] = __builtin_amdgcn_mfma_f32_16x16x32_bf16(af[mt], bf[nt], acc[mt][nt], 0, 0, 0);
    __syncthreads();
  }

#pragma unroll
  for (int mt = 0; mt < 4; ++mt) {
    const int row = bm + wm + mt * 16 + quad * 4;
#pragma unroll
    for (int nt = 0; nt < 4; ++nt) {
      const int col = bn + wn + nt * 16 + l16;
      f32x4 v = acc[mt][nt];
      if (col < 2048) {
        const float bias = (col < 1024) ? bq[col] : bk[col - 1024];
        const float sc = (col < 1024) ? 0.18033688011f : 1.0f;  // 0.125*log2(e)
#pragma unroll
        for (int r = 0; r < 4; ++r)
          QKo[(size_t)(row + r) * 2048 + col] = (__hip_bfloat16)((v[r] + bias) * sc);
      } else {
        const int cv = col - 2048;
        const float bias = bv[cv];
        const int hh = cv >> 6, d = cv & 63;
        const int bb = row >> 11, s0 = row & 2047;
        union { __hip_bfloat16 h[4]; unsigned long long u; } pk;
#pragma unroll
        for (int r = 0; r < 4; ++r) pk.h[r] = (__hip_bfloat16)(v[r] + bias);
        *(unsigned long long*)(Vt + ((size_t)(bb * 16 + hh) * 64 + d) * 2048 + s0) = pk.u;
      }
    }
  }
}

// ---------------------------------------------------------------------------
// Out-proj GEMM (m97 structure), fp32 output.
// ---------------------------------------------------------------------------
__global__ __launch_bounds__(256) void gemm_out(
    const __hip_bfloat16* __restrict__ A,
    const __hip_bfloat16* __restrict__ Bt,
    const float* __restrict__ b0,
    float* __restrict__ C,
    int N, int K) {
  __shared__ __hip_bfloat16 sA[128 * 32];
  __shared__ __hip_bfloat16 sB[128 * 32];
  const int tid  = threadIdx.x;
  const int wave = tid >> 6;
  const int lane = tid & 63;
  const int quad = lane >> 4;
  const int l16  = lane & 15;
  const int bm = blockIdx.y * 128;
  const int bn = blockIdx.x * 128;
  const int wm = (wave >> 1) * 64;
  const int wn = (wave & 1) * 64;

  const int r0 = wave * 2, r1 = wave * 2 + 1;
  const int lrow = lane >> 2;
  const int lcol = (lane & 3) * 8;

  const __hip_bfloat16* ga0 = A  + (size_t)(bm + r0 * 16 + lrow) * K + lcol;
  const __hip_bfloat16* ga1 = A  + (size_t)(bm + r1 * 16 + lrow) * K + lcol;
  const __hip_bfloat16* gb0 = Bt + (size_t)(bn + r0 * 16 + lrow) * K + lcol;
  const __hip_bfloat16* gb1 = Bt + (size_t)(bn + r1 * 16 + lrow) * K + lcol;
  char* la0 = (char*)sA + r0 * 1024;
  char* la1 = (char*)sA + r1 * 1024;
  char* lb0 = (char*)sB + r0 * 1024;
  char* lb1 = (char*)sB + r1 * 1024;

  const char* pa = (const char*)sA + (wm + l16) * 64 + quad * 16;
  const char* pb = (const char*)sB + (wn + l16) * 64 + quad * 16;

  f32x4 acc[4][4] = {};

  for (int k0 = 0; k0 < K; k0 += 32) {
    async16(ga0 + k0, la0);
    async16(ga1 + k0, la1);
    async16(gb0 + k0, lb0);
    async16(gb1 + k0, lb1);
    __syncthreads();
    bf16x8 af[4], bf[4];
#pragma unroll
    for (int mt = 0; mt < 4; ++mt) af[mt] = *(const bf16x8*)(pa + mt * 1024);
#pragma unroll
    for (int nt = 0; nt < 4; ++nt) bf[nt] = *(const bf16x8*)(pb + nt * 1024);
#pragma unroll
    for (int mt = 0; mt < 4; ++mt)
#pragma unroll
      for (int nt = 0; nt < 4; ++nt)
        acc[mt][nt] = __builtin_amdgcn_mfma_f32_16x16x32_bf16(af[mt], bf[nt], acc[mt][nt], 0, 0, 0);
    __syncthreads();
  }

#pragma unroll
  for (int mt = 0; mt < 4; ++mt) {
    const int row = bm + wm + mt * 16 + quad * 4;
#pragma unroll
    for (int nt = 0; nt < 4; ++nt) {
      const int col = bn + wn + nt * 16 + l16;
      const float bias = b0[col];
      f32x4 v = acc[mt][nt];
#pragma unroll
      for (int r = 0; r < 4; ++r)
        C[(size_t)(row + r) * N + col] = v[r] + bias;
    }
  }
}

// ---------------------------------------------------------------------------
// Flash attention v10 = v9 + counted-vmcnt pipeline (T3/T4):
//  - prologue stages tiles 0 AND 1; per-tile sync is asm vmcnt(2) + raw
//    s_barrier (no vmcnt(0) drain in the loop); tile kt+2's DMA is issued
//    after the barrier (all waves done reading buf[cur]) -> each DMA gets
//    ~1.8 iterations of latency cover instead of one force-drained phase.
//  - vmcnt model (pinned by asm "" memory fences + #pragma unroll 1):
//    at the wait, outstanding = [4 DMAs tile kt+1 (oldest)] + [2 mask
//    loads] -> vmcnt(2) retires exactly the DMAs.
//  - LDS read-vs-overwrite safety: all ds_read results are consumed by
//    MFMAs before the barrier (compiler-inserted lgkmcnt), DMA issue is
//    after the barrier.
// ---------------------------------------------------------------------------
__global__ __launch_bounds__(256, 4) void flash_attn(
    const __hip_bfloat16* __restrict__ QK,            // [8192][2048]
    const __hip_bfloat16* __restrict__ Vt,            // [B*H*64][2048]
    const uint4* __restrict__ XM,                     // expanded masks
    __hip_bfloat16* __restrict__ O) {                 // [8192][1024]
  __shared__ __hip_bfloat16 sK[2][64 * 64];
  __shared__ __hip_bfloat16 sV[2][64 * 64];

  const int qt = blockIdx.x, h = blockIdx.y, b = blockIdx.z;
  const int tid = threadIdx.x;
  const int wave = tid >> 6, lane = tid & 63, quad = lane >> 4, l16 = lane & 15;
  const int qbase = qt * 128;
  const size_t brow = (size_t)b * S_;
  const int bh = b * H_ + h;

  // Q fragments direct from global: B-operand, lane n = l16 = q row.
  bf16x8 qf[2][2];
#pragma unroll
  for (int g = 0; g < 2; ++g) {
    const __hip_bfloat16* qrow =
        QK + (brow + qbase + g * 64 + wave * 16 + l16) * 2048 + h * 64;
#pragma unroll
    for (int c = 0; c < 2; ++c)
      qf[g][c] = *(const bf16x8*)(qrow + c * 32 + quad * 8);
  }

  // DMA staging: lane i of instr t covers row wave*16 + t*8 + (i>>3),
  // physical chunk i&7 = logical chunk (i&7)^(i>>3) (XOR swizzle).
  const int srow = lane >> 3;
  const int schk = (lane & 7) ^ srow;
  const __hip_bfloat16* gk0 =
      QK + (brow + wave * 16 + srow) * 2048 + 1024 + h * 64 + schk * 8;
  const __hip_bfloat16* gk1 = gk0 + (size_t)8 * 2048;
  const __hip_bfloat16* gv0 =
      Vt + ((size_t)bh * 64 + wave * 16 + srow) * 2048 + schk * 8;
  const __hip_bfloat16* gv1 = gv0 + (size_t)8 * 2048;
  char* const lK[2] = {(char*)&sK[0][0] + wave * 2048, (char*)&sK[1][0] + wave * 2048};
  char* const lV[2] = {(char*)&sV[0][0] + wave * 2048, (char*)&sV[1][0] + wave * 2048};

  // expanded-mask pointers: per q-row 256 uint4; per kt 8; per quad 2.
  const uint4* xpa = XM + ((brow + qbase + wave * 16 + l16) * 256 + quad * 2);
  const uint4* xpb = xpa + (size_t)64 * 256;

  // fragment-read swizzle offsets (chunk c*4+quad, row parity l16&7)
  const int xl = l16 & 7;
  const int koff0 = ((quad ^ xl) * 16);        // c=0 chunk; c=1 = koff0^64
  const int rowb = l16 * 128;

  const bf16x8 onesv = {(short)0x3F80, (short)0x3F80, (short)0x3F80, (short)0x3F80,
                        (short)0x3F80, (short)0x3F80, (short)0x3F80, (short)0x3F80};
  f32x4 lacc[2] = {};
  f32x4 oacc[2][4] = {};

  // prologue: stage tiles 0 AND 1, prefetch tile-0 masks, wait for tile 0
  async16(gk0, lK[0]);
  async16(gk1, lK[0] + 1024);
  async16(gv0, lV[0]);
  async16(gv1, lV[0] + 1024);
  gk0 += (size_t)64 * 2048; gk1 += (size_t)64 * 2048;
  gv0 += 64; gv1 += 64;
  asm volatile("" ::: "memory");
  async16(gk0, lK[1]);
  async16(gk1, lK[1] + 1024);
  async16(gv0, lV[1]);
  async16(gv1, lV[1] + 1024);
  gk0 += (size_t)64 * 2048; gk1 += (size_t)64 * 2048;
  gv0 += 64; gv1 += 64;
  asm volatile("" ::: "memory");
  uint4 x0a = xpa[0], x1a = xpa[1], x0b = xpb[0], x1b = xpb[1];
  // >=6 VMEM ops (tile-1 DMAs + mask loads) are pinned newer than tile-0's
  // DMAs -> vmcnt(6) guarantees tile 0 landed.
  asm volatile("s_waitcnt vmcnt(6)" ::: "memory");
  __builtin_amdgcn_s_barrier();

  const int NT = S_ / 64;
#pragma unroll 1
  for (int kt = 0; kt < NT; ++kt) {
    const int cur = kt & 1;
    const uint4 ca0 = x0a, ca1 = x1a, cb0 = x0b, cb1 = x1b;
    const int kn = (kt + 1 < NT) ? kt + 1 : kt;
    x0a = xpa[kn * 8]; x1a = xpa[kn * 8 + 1];
    x0b = xpb[kn * 8]; x1b = xpb[kn * 8 + 1];

    // QK with fused exp/pack/AND-mask: kf read once feeds both q-groups.
    const char* bK = (const char*)&sK[cur][0] + rowb;
    unsigned pl[2][4][2];
#pragma unroll
    for (int mt = 0; mt < 4; ++mt) {
      const bf16x8 kf0 = *(const bf16x8*)(bK + mt * 2048 + koff0);
      const bf16x8 kf1 = *(const bf16x8*)(bK + mt * 2048 + (koff0 ^ 64));
      f32x4 a0 = {}, a1 = {};
      __builtin_amdgcn_s_setprio(1);
      a0 = __builtin_amdgcn_mfma_f32_16x16x32_bf16(kf0, qf[0][0], a0, 0, 0, 0);
      a0 = __builtin_amdgcn_mfma_f32_16x16x32_bf16(kf1, qf[0][1], a0, 0, 0, 0);
      a1 = __builtin_amdgcn_mfma_f32_16x16x32_bf16(kf0, qf[1][0], a1, 0, 0, 0);
      a1 = __builtin_amdgcn_mfma_f32_16x16x32_bf16(kf1, qf[1][1], a1, 0, 0, 0);
      __builtin_amdgcn_s_setprio(0);
#pragma unroll
      for (int g = 0; g < 2; ++g) {
        const uint4 cc = g ? ((mt < 2) ? cb0 : cb1) : ((mt < 2) ? ca0 : ca1);
        const unsigned w0 = (mt & 1) ? cc.z : cc.x;
        const unsigned w1 = (mt & 1) ? cc.w : cc.y;
        const f32x4 av = g ? a1 : a0;
        union { __hip_bfloat16 h[2]; unsigned u; } c0, c1;
        c0.h[0] = (__hip_bfloat16)__builtin_amdgcn_exp2f(av[0]);
        c0.h[1] = (__hip_bfloat16)__builtin_amdgcn_exp2f(av[1]);
        c1.h[0] = (__hip_bfloat16)__builtin_amdgcn_exp2f(av[2]);
        c1.h[1] = (__hip_bfloat16)__builtin_amdgcn_exp2f(av[3]);
        pl[g][mt][0] = c0.u & w0;
        pl[g][mt][1] = c1.u & w1;
      }
    }

    // In-register P^T -> B-operand redistribution (permlane swaps).
    // VDST = even-mt word (E), SRC0 = odd-mt word (O); after the two swaps
    // E = pf words {0,1}, O = pf words {2,3}.
    bf16x8 pf[2][2];
#pragma unroll
    for (int g = 0; g < 2; ++g)
#pragma unroll
      for (int c = 0; c < 2; ++c) {
        unsigned e0 = pl[g][2 * c][0], o0 = pl[g][2 * c + 1][0];
        unsigned e1 = pl[g][2 * c][1], o1 = pl[g][2 * c + 1][1];
        asm("v_permlane32_swap_b32 %0, %1" : "+v"(e0), "+v"(o0));
        asm("v_permlane16_swap_b32 %0, %1" : "+v"(e0), "+v"(o0));
        asm("v_permlane32_swap_b32 %0, %1" : "+v"(e1), "+v"(o1));
        asm("v_permlane16_swap_b32 %0, %1" : "+v"(e1), "+v"(o1));
        union { unsigned u[4]; bf16x8 v; } uu;
        uu.u[0] = e0; uu.u[1] = e1; uu.u[2] = o0; uu.u[3] = o1;
        pf[g][c] = uu.v;
      }

    // PV: O^T += V^T · P^T ; vf read once, feeds both groups.
    const char* bV = (const char*)&sV[cur][0] + rowb;
    __builtin_amdgcn_s_setprio(1);
#pragma unroll
    for (int ht = 0; ht < 4; ++ht) {
      const bf16x8 vf0 = *(const bf16x8*)(bV + ht * 2048 + koff0);
      const bf16x8 vf1 = *(const bf16x8*)(bV + ht * 2048 + (koff0 ^ 64));
      oacc[0][ht] = __builtin_amdgcn_mfma_f32_16x16x32_bf16(vf0, pf[0][0], oacc[0][ht], 0, 0, 0);
      oacc[0][ht] = __builtin_amdgcn_mfma_f32_16x16x32_bf16(vf1, pf[0][1], oacc[0][ht], 0, 0, 0);
      oacc[1][ht] = __builtin_amdgcn_mfma_f32_16x16x32_bf16(vf0, pf[1][0], oacc[1][ht], 0, 0, 0);
      oacc[1][ht] = __builtin_amdgcn_mfma_f32_16x16x32_bf16(vf1, pf[1][1], oacc[1][ht], 0, 0, 0);
    }
    // l row-sums via ones-MFMA: D[r][q] = sum_k P[k][q] for every r.
    lacc[0] = __builtin_amdgcn_mfma_f32_16x16x32_bf16(onesv, pf[0][0], lacc[0], 0, 0, 0);
    lacc[0] = __builtin_amdgcn_mfma_f32_16x16x32_bf16(onesv, pf[0][1], lacc[0], 0, 0, 0);
    lacc[1] = __builtin_amdgcn_mfma_f32_16x16x32_bf16(onesv, pf[1][0], lacc[1], 0, 0, 0);
    lacc[1] = __builtin_amdgcn_mfma_f32_16x16x32_bf16(onesv, pf[1][1], lacc[1], 0, 0, 0);
    __builtin_amdgcn_s_setprio(0);

    if (kt + 1 < NT) {
      // tile kt+1's 4 DMAs retired; the 2 mask loads may stay in flight
      asm volatile("s_waitcnt vmcnt(2)" ::: "memory");
      __builtin_amdgcn_s_barrier();
      if (kt + 2 < NT) {
        // all waves past reading buf[cur] -> safe to overwrite with kt+2
        async16(gk0, lK[cur]);
        async16(gk1, lK[cur] + 1024);
        async16(gv0, lV[cur]);
        async16(gv1, lV[cur] + 1024);
        gk0 += (size_t)64 * 2048; gk1 += (size_t)64 * 2048;
        gv0 += 64; gv1 += 64;
      }
      asm volatile("" ::: "memory");
    }
  }

  // epilogue: every lane holds its q-column's sum in lacc[g][*]
#pragma unroll
  for (int g = 0; g < 2; ++g) {
    const float l = lacc[g][0];
    const float inv = (l > 0.f) ? 1.f / l : 0.f;
    __hip_bfloat16* orow =
        O + (brow + qbase + g * 64 + wave * 16 + l16) * 1024 + h * 64;
#pragma unroll
    for (int ht = 0; ht < 4; ++ht) {
      union { __hip_bfloat16 h[4]; unsigned long long u; } ok_;
#pragma unroll
      for (int r = 0; r < 4; ++r) ok_.h[r] = (__hip_bfloat16)(oacc[g][ht][r] * inv);
      *(unsigned long long*)(orow + ht * 16 + quad * 4) = ok_.u;
    }
  }
}

// ---------------------------------------------------------------------------
extern "C" void kernel_launch(void* const* d_in, const int* in_sizes, int n_in,
                              void* d_out, int out_size, void* d_ws, size_t ws_size,
                              hipStream_t stream) {
  const float* x  = (const float*)d_in[0];
  const int*   mk = (const int*)d_in[1];
  const float* Wq = (const float*)d_in[2];
  const float* bq = (const float*)d_in[3];
  const float* Wk = (const float*)d_in[4];
  const float* bk = (const float*)d_in[5];
  const float* Wv = (const float*)d_in[6];
  const float* bv = (const float*)d_in[7];
  const float* Wo = (const float*)d_in[8];
  const float* bo = (const float*)d_in[9];
  float* out = (float*)d_out;

  __hip_bfloat16* X16    = (__hip_bfloat16*)d_ws;                  // [8192][1024]
  __hip_bfloat16* Wt_qkv = X16 + (size_t)B_ * S_ * D_;             // [3072][1024]
  __hip_bfloat16* Wt_o   = Wt_qkv + (size_t)3 * D_ * D_;           // [1024][1024]
  __hip_bfloat16* QK     = Wt_o + (size_t)D_ * D_;                 // [8192][2048]
  __hip_bfloat16* Vt     = QK + (size_t)B_ * S_ * 2 * D_;          // [4096][2048]
  __hip_bfloat16* Obuf   = Vt + (size_t)B_ * H_ * HD_ * S_;        // [8192][1024]
  unsigned* xmask = (unsigned*)(Obuf + (size_t)B_ * S_ * D_);      // 33.5 MB

  const int nx = B_ * S_ * D_;
  cvt_x<<<dim3((nx / 4 + 255) / 256), 256, 0, stream>>>(x, X16, nx);
  transpose_w<<<dim3(32, 32, 4), dim3(32, 32), 0, stream>>>(Wq, Wk, Wv, Wo, Wt_qkv, Wt_o);
  expand_mask<<<dim3((int)((size_t)B_ * S_ * S_ / 4 / 256)), 256, 0, stream>>>(
      mk, (uint2*)xmask);
  gemm_qkv<<<dim3(3 * D_ / 128, B_ * S_ / 128), 256, 0, stream>>>(
      X16, Wt_qkv, bq, bk, bv, QK, Vt);
  flash_attn<<<dim3(S_ / 128, H_, B_), 256, 0, stream>>>(
      QK, Vt, (const uint4*)xmask, Obuf);
  gemm_out<<<dim3(D_ / 128, B_ * S_ / 128), 256, 0, stream>>>(
      Obuf, Wt_o, bo, out, D_, D_);
}

// Round 6
// 360.191 us; speedup vs baseline: 1.0707x; 1.0707x over previous
//
#include <hip/hip_runtime.h>
#include <hip/hip_bf16.h>
#include <stdint.h>

#define B_  4
#define S_  2048
#define D_  1024
#define H_  16
#define HD_ 64

typedef __attribute__((ext_vector_type(4))) float f32x4;
typedef __attribute__((ext_vector_type(8))) short bf16x8;

typedef const unsigned int __attribute__((address_space(1)))* gas_ptr;
typedef unsigned int __attribute__((address_space(3)))* las_ptr;

__device__ __forceinline__ void async16(const void* g, void* l) {
  __builtin_amdgcn_global_load_lds((gas_ptr)g, (las_ptr)l, 16, 0, 0);
}

// ---------------------------------------------------------------------------
// x fp32 -> bf16
// ---------------------------------------------------------------------------
__global__ __launch_bounds__(256) void cvt_x(const float* __restrict__ in,
                                             __hip_bfloat16* __restrict__ out,
                                             int n) {
  const int i = (blockIdx.x * blockDim.x + threadIdx.x) * 4;
  if (i >= n) return;
  const float4 v = *(const float4*)(in + i);
  union { ushort4 u; __hip_bfloat16 h[4]; } o;
  o.h[0] = (__hip_bfloat16)v.x;
  o.h[1] = (__hip_bfloat16)v.y;
  o.h[2] = (__hip_bfloat16)v.z;
  o.h[3] = (__hip_bfloat16)v.w;
  *(ushort4*)(out + i) = o.u;
}

// ---------------------------------------------------------------------------
// mask int32 -> expanded bf16-AND masks (0xFFFF keep / 0x0000 drop), laid out
// exactly as flash_attn's packed-P pairs consume them:
//   u32 index = ((((b*2048+q)*32 + kt)*4 + quad)*8) + mt*2 + h
// ---------------------------------------------------------------------------
__global__ __launch_bounds__(256) void expand_mask(const int* __restrict__ mk,
                                                   uint2* __restrict__ xm) {
  const unsigned j = blockIdx.x * 256 + threadIdx.x;
  const int mt = j & 3, quad = (j >> 2) & 3, kt = (j >> 4) & 31;
  const int q = (j >> 9) & 2047, b = j >> 20;
  const size_t row = (size_t)b * 2048 + q;
  const int key = kt * 64 + mt * 16 + quad * 4;
  const int4 m = *(const int4*)(mk + row * 2048 + key);
  uint2 o;
  o.x = (m.x ? 0xFFFFu : 0u) | (m.y ? 0xFFFF0000u : 0u);
  o.y = (m.z ? 0xFFFFu : 0u) | (m.w ? 0xFFFF0000u : 0u);
  xm[j] = o;
}

// ---------------------------------------------------------------------------
// weights fp32 [K,N] -> bf16 transposed [N,K]
// ---------------------------------------------------------------------------
__global__ void transpose_w(const float* __restrict__ Wq,
                            const float* __restrict__ Wk,
                            const float* __restrict__ Wv,
                            const float* __restrict__ Wo,
                            __hip_bfloat16* __restrict__ Wt_qkv,
                            __hip_bfloat16* __restrict__ Wt_o) {
  __shared__ float t[32][33];
  const int z = blockIdx.z;
  const float* W = (z == 0) ? Wq : (z == 1) ? Wk : (z == 2) ? Wv : Wo;
  __hip_bfloat16* Wt = (z < 3) ? (Wt_qkv + (size_t)z * D_ * D_) : Wt_o;
  const int x = blockIdx.x * 32 + threadIdx.x;
  const int y = blockIdx.y * 32 + threadIdx.y;
  t[threadIdx.y][threadIdx.x] = W[(size_t)y * D_ + x];
  __syncthreads();
  const int xo = blockIdx.y * 32 + threadIdx.x;
  const int yo = blockIdx.x * 32 + threadIdx.y;
  Wt[(size_t)yo * D_ + xo] = (__hip_bfloat16)t[threadIdx.x][threadIdx.y];
}

// ---------------------------------------------------------------------------
// QKV GEMM: C[8192,3072] = X16 @ Wt_qkv^T + bias. Q cols scaled by
// 0.125*log2(e) (softmax scale folded into Q). Q,K -> QKo [8192][2048];
// V -> Vt [B*H*64][2048] (pre-transposed for flash A-operand use).
// 1D grid + bijective XCD swizzle (T1): each XCD gets 8 contiguous M-tile
// rows (A-panel reuse ~2MB/XCD-L2); nwg=1536, 1536%8==0.
// ---------------------------------------------------------------------------
__global__ __launch_bounds__(256) void gemm_qkv(
    const __hip_bfloat16* __restrict__ A,
    const __hip_bfloat16* __restrict__ Bt,
    const float* __restrict__ bq,
    const float* __restrict__ bk,
    const float* __restrict__ bv,
    __hip_bfloat16* __restrict__ QKo,
    __hip_bfloat16* __restrict__ Vt) {
  __shared__ __hip_bfloat16 sA[128 * 32];
  __shared__ __hip_bfloat16 sB[128 * 32];
  const int K = 1024;
  const int tid  = threadIdx.x;
  const int wave = tid >> 6;
  const int lane = tid & 63;
  const int quad = lane >> 4;
  const int l16  = lane & 15;
  // XCD swizzle: nwg = 24*64 = 1536, chunk = 192 per XCD (8 M-rows of 24)
  const int wg  = blockIdx.x;
  const int swz = (wg & 7) * 192 + (wg >> 3);
  const int bm = (swz / 24) * 128;
  const int bn = (swz % 24) * 128;
  const int wm = (wave >> 1) * 64;
  const int wn = (wave & 1) * 64;

  const int r0 = wave * 2, r1 = wave * 2 + 1;
  const int lrow = lane >> 2;
  const int lcol = (lane & 3) * 8;

  const __hip_bfloat16* ga0 = A  + (size_t)(bm + r0 * 16 + lrow) * K + lcol;
  const __hip_bfloat16* ga1 = A  + (size_t)(bm + r1 * 16 + lrow) * K + lcol;
  const __hip_bfloat16* gb0 = Bt + (size_t)(bn + r0 * 16 + lrow) * K + lcol;
  const __hip_bfloat16* gb1 = Bt + (size_t)(bn + r1 * 16 + lrow) * K + lcol;
  char* la0 = (char*)sA + r0 * 1024;
  char* la1 = (char*)sA + r1 * 1024;
  char* lb0 = (char*)sB + r0 * 1024;
  char* lb1 = (char*)sB + r1 * 1024;

  const char* pa = (const char*)sA + (wm + l16) * 64 + quad * 16;
  const char* pb = (const char*)sB + (wn + l16) * 64 + quad * 16;

  f32x4 acc[4][4] = {};

  for (int k0 = 0; k0 < K; k0 += 32) {
    async16(ga0 + k0, la0);
    async16(ga1 + k0, la1);
    async16(gb0 + k0, lb0);
    async16(gb1 + k0, lb1);
    __syncthreads();
    bf16x8 af[4], bf[4];
#pragma unroll
    for (int mt = 0; mt < 4; ++mt) af[mt] = *(const bf16x8*)(pa + mt * 1024);
#pragma unroll
    for (int nt = 0; nt < 4; ++nt) bf[nt] = *(const bf16x8*)(pb + nt * 1024);
#pragma unroll
    for (int mt = 0; mt < 4; ++mt)
#pragma unroll
      for (int nt = 0; nt < 4; ++nt)
        acc[mt][nt] = __builtin_amdgcn_mfma_f32_16x16x32_bf16(af[mt], bf[nt], acc[mt][nt], 0, 0, 0);
    __syncthreads();
  }

#pragma unroll
  for (int mt = 0; mt < 4; ++mt) {
    const int row = bm + wm + mt * 16 + quad * 4;
#pragma unroll
    for (int nt = 0; nt < 4; ++nt) {
      const int col = bn + wn + nt * 16 + l16;
      f32x4 v = acc[mt][nt];
      if (col < 2048) {
        const float bias = (col < 1024) ? bq[col] : bk[col - 1024];
        const float sc = (col < 1024) ? 0.18033688011f : 1.0f;  // 0.125*log2(e)
#pragma unroll
        for (int r = 0; r < 4; ++r)
          QKo[(size_t)(row + r) * 2048 + col] = (__hip_bfloat16)((v[r] + bias) * sc);
      } else {
        const int cv = col - 2048;
        const float bias = bv[cv];
        const int hh = cv >> 6, d = cv & 63;
        const int bb = row >> 11, s0 = row & 2047;
        union { __hip_bfloat16 h[4]; unsigned long long u; } pk;
#pragma unroll
        for (int r = 0; r < 4; ++r) pk.h[r] = (__hip_bfloat16)(v[r] + bias);
        *(unsigned long long*)(Vt + ((size_t)(bb * 16 + hh) * 64 + d) * 2048 + s0) = pk.u;
      }
    }
  }
}

// ---------------------------------------------------------------------------
// Out-proj GEMM (m97 structure), fp32 output. 1D grid + XCD swizzle
// (nwg = 8*64 = 512, chunk = 64 per XCD = 8 M-rows of 8).
// ---------------------------------------------------------------------------
__global__ __launch_bounds__(256) void gemm_out(
    const __hip_bfloat16* __restrict__ A,
    const __hip_bfloat16* __restrict__ Bt,
    const float* __restrict__ b0,
    float* __restrict__ C,
    int N, int K) {
  __shared__ __hip_bfloat16 sA[128 * 32];
  __shared__ __hip_bfloat16 sB[128 * 32];
  const int tid  = threadIdx.x;
  const int wave = tid >> 6;
  const int lane = tid & 63;
  const int quad = lane >> 4;
  const int l16  = lane & 15;
  const int wg  = blockIdx.x;
  const int swz = (wg & 7) * 64 + (wg >> 3);
  const int bm = (swz >> 3) * 128;
  const int bn = (swz & 7) * 128;
  const int wm = (wave >> 1) * 64;
  const int wn = (wave & 1) * 64;

  const int r0 = wave * 2, r1 = wave * 2 + 1;
  const int lrow = lane >> 2;
  const int lcol = (lane & 3) * 8;

  const __hip_bfloat16* ga0 = A  + (size_t)(bm + r0 * 16 + lrow) * K + lcol;
  const __hip_bfloat16* ga1 = A  + (size_t)(bm + r1 * 16 + lrow) * K + lcol;
  const __hip_bfloat16* gb0 = Bt + (size_t)(bn + r0 * 16 + lrow) * K + lcol;
  const __hip_bfloat16* gb1 = Bt + (size_t)(bn + r1 * 16 + lrow) * K + lcol;
  char* la0 = (char*)sA + r0 * 1024;
  char* la1 = (char*)sA + r1 * 1024;
  char* lb0 = (char*)sB + r0 * 1024;
  char* lb1 = (char*)sB + r1 * 1024;

  const char* pa = (const char*)sA + (wm + l16) * 64 + quad * 16;
  const char* pb = (const char*)sB + (wn + l16) * 64 + quad * 16;

  f32x4 acc[4][4] = {};

  for (int k0 = 0; k0 < K; k0 += 32) {
    async16(ga0 + k0, la0);
    async16(ga1 + k0, la1);
    async16(gb0 + k0, lb0);
    async16(gb1 + k0, lb1);
    __syncthreads();
    bf16x8 af[4], bf[4];
#pragma unroll
    for (int mt = 0; mt < 4; ++mt) af[mt] = *(const bf16x8*)(pa + mt * 1024);
#pragma unroll
    for (int nt = 0; nt < 4; ++nt) bf[nt] = *(const bf16x8*)(pb + nt * 1024);
#pragma unroll
    for (int mt = 0; mt < 4; ++mt)
#pragma unroll
      for (int nt = 0; nt < 4; ++nt)
        acc[mt][nt] = __builtin_amdgcn_mfma_f32_16x16x32_bf16(af[mt], bf[nt], acc[mt][nt], 0, 0, 0);
    __syncthreads();
  }

#pragma unroll
  for (int mt = 0; mt < 4; ++mt) {
    const int row = bm + wm + mt * 16 + quad * 4;
#pragma unroll
    for (int nt = 0; nt < 4; ++nt) {
      const int col = bn + wn + nt * 16 + l16;
      const float bias = b0[col];
      f32x4 v = acc[mt][nt];
#pragma unroll
      for (int r = 0; r < 4; ++r)
        C[(size_t)(row + r) * N + col] = v[r] + bias;
    }
  }
}

// ---------------------------------------------------------------------------
// Flash attention v9 (reverted from v10: counted-vmcnt regressed 114->131us;
// asm fences defeated compiler scheduling and block-level overlap already
// covered the barrier drain). Proven structure: stage nxt at loop top,
// __syncthreads at bottom; in-register permlane P^T repack; pre-expanded
// AND masks; ones-MFMA l row-sums; setprio around MFMA clusters.
// ---------------------------------------------------------------------------
__global__ __launch_bounds__(256, 4) void flash_attn(
    const __hip_bfloat16* __restrict__ QK,            // [8192][2048]
    const __hip_bfloat16* __restrict__ Vt,            // [B*H*64][2048]
    const uint4* __restrict__ XM,                     // expanded masks
    __hip_bfloat16* __restrict__ O) {                 // [8192][1024]
  __shared__ __hip_bfloat16 sK[2][64 * 64];
  __shared__ __hip_bfloat16 sV[2][64 * 64];

  const int qt = blockIdx.x, h = blockIdx.y, b = blockIdx.z;
  const int tid = threadIdx.x;
  const int wave = tid >> 6, lane = tid & 63, quad = lane >> 4, l16 = lane & 15;
  const int qbase = qt * 128;
  const size_t brow = (size_t)b * S_;
  const int bh = b * H_ + h;

  // Q fragments direct from global: B-operand, lane n = l16 = q row.
  bf16x8 qf[2][2];
#pragma unroll
  for (int g = 0; g < 2; ++g) {
    const __hip_bfloat16* qrow =
        QK + (brow + qbase + g * 64 + wave * 16 + l16) * 2048 + h * 64;
#pragma unroll
    for (int c = 0; c < 2; ++c)
      qf[g][c] = *(const bf16x8*)(qrow + c * 32 + quad * 8);
  }

  // DMA staging: lane i of instr t covers row wave*16 + t*8 + (i>>3),
  // physical chunk i&7 = logical chunk (i&7)^(i>>3) (XOR swizzle).
  const int srow = lane >> 3;
  const int schk = (lane & 7) ^ srow;
  const __hip_bfloat16* gk0 =
      QK + (brow + wave * 16 + srow) * 2048 + 1024 + h * 64 + schk * 8;
  const __hip_bfloat16* gk1 = gk0 + (size_t)8 * 2048;
  const __hip_bfloat16* gv0 =
      Vt + ((size_t)bh * 64 + wave * 16 + srow) * 2048 + schk * 8;
  const __hip_bfloat16* gv1 = gv0 + (size_t)8 * 2048;
  char* const lK[2] = {(char*)&sK[0][0] + wave * 2048, (char*)&sK[1][0] + wave * 2048};
  char* const lV[2] = {(char*)&sV[0][0] + wave * 2048, (char*)&sV[1][0] + wave * 2048};

  // expanded-mask pointers: per q-row 256 uint4; per kt 8; per quad 2.
  const uint4* xpa = XM + ((brow + qbase + wave * 16 + l16) * 256 + quad * 2);
  const uint4* xpb = xpa + (size_t)64 * 256;

  // fragment-read swizzle offsets (chunk c*4+quad, row parity l16&7)
  const int xl = l16 & 7;
  const int koff0 = ((quad ^ xl) * 16);        // c=0 chunk; c=1 = koff0^64
  const int rowb = l16 * 128;

  const bf16x8 onesv = {(short)0x3F80, (short)0x3F80, (short)0x3F80, (short)0x3F80,
                        (short)0x3F80, (short)0x3F80, (short)0x3F80, (short)0x3F80};
  f32x4 lacc[2] = {};
  f32x4 oacc[2][4] = {};

  // prologue: stage tile 0, prefetch tile-0 mask words
  async16(gk0, lK[0]);
  async16(gk1, lK[0] + 1024);
  async16(gv0, lV[0]);
  async16(gv1, lV[0] + 1024);
  uint4 x0a = xpa[0], x1a = xpa[1], x0b = xpb[0], x1b = xpb[1];
  gk0 += (size_t)64 * 2048; gk1 += (size_t)64 * 2048;
  gv0 += 64; gv1 += 64;
  __syncthreads();

  const int NT = S_ / 64;
  for (int kt = 0; kt < NT; ++kt) {
    const int cur = kt & 1, nxt = cur ^ 1;

    // issue next tile's DMA (overlaps this tile's compute; disjoint buffer)
    if (kt + 1 < NT) {
      async16(gk0, lK[nxt]);
      async16(gk1, lK[nxt] + 1024);
      async16(gv0, lV[nxt]);
      async16(gv1, lV[nxt] + 1024);
      gk0 += (size_t)64 * 2048; gk1 += (size_t)64 * 2048;
      gv0 += 64; gv1 += 64;
    }
    const uint4 ca0 = x0a, ca1 = x1a, cb0 = x0b, cb1 = x1b;
    const int kn = (kt + 1 < NT) ? kt + 1 : kt;
    x0a = xpa[kn * 8]; x1a = xpa[kn * 8 + 1];
    x0b = xpb[kn * 8]; x1b = xpb[kn * 8 + 1];

    // QK with fused exp/pack/AND-mask: kf read once feeds both q-groups.
    const char* bK = (const char*)&sK[cur][0] + rowb;
    unsigned pl[2][4][2];
#pragma unroll
    for (int mt = 0; mt < 4; ++mt) {
      const bf16x8 kf0 = *(const bf16x8*)(bK + mt * 2048 + koff0);
      const bf16x8 kf1 = *(const bf16x8*)(bK + mt * 2048 + (koff0 ^ 64));
      f32x4 a0 = {}, a1 = {};
      __builtin_amdgcn_s_setprio(1);
      a0 = __builtin_amdgcn_mfma_f32_16x16x32_bf16(kf0, qf[0][0], a0, 0, 0, 0);
      a0 = __builtin_amdgcn_mfma_f32_16x16x32_bf16(kf1, qf[0][1], a0, 0, 0, 0);
      a1 = __builtin_amdgcn_mfma_f32_16x16x32_bf16(kf0, qf[1][0], a1, 0, 0, 0);
      a1 = __builtin_amdgcn_mfma_f32_16x16x32_bf16(kf1, qf[1][1], a1, 0, 0, 0);
      __builtin_amdgcn_s_setprio(0);
#pragma unroll
      for (int g = 0; g < 2; ++g) {
        const uint4 cc = g ? ((mt < 2) ? cb0 : cb1) : ((mt < 2) ? ca0 : ca1);
        const unsigned w0 = (mt & 1) ? cc.z : cc.x;
        const unsigned w1 = (mt & 1) ? cc.w : cc.y;
        const f32x4 av = g ? a1 : a0;
        union { __hip_bfloat16 h[2]; unsigned u; } c0, c1;
        c0.h[0] = (__hip_bfloat16)__builtin_amdgcn_exp2f(av[0]);
        c0.h[1] = (__hip_bfloat16)__builtin_amdgcn_exp2f(av[1]);
        c1.h[0] = (__hip_bfloat16)__builtin_amdgcn_exp2f(av[2]);
        c1.h[1] = (__hip_bfloat16)__builtin_amdgcn_exp2f(av[3]);
        pl[g][mt][0] = c0.u & w0;
        pl[g][mt][1] = c1.u & w1;
      }
    }

    // In-register P^T -> B-operand redistribution (permlane swaps).
    // VDST = even-mt word (E), SRC0 = odd-mt word (O); after the two swaps
    // E = pf words {0,1}, O = pf words {2,3}.
    bf16x8 pf[2][2];
#pragma unroll
    for (int g = 0; g < 2; ++g)
#pragma unroll
      for (int c = 0; c < 2; ++c) {
        unsigned e0 = pl[g][2 * c][0], o0 = pl[g][2 * c + 1][0];
        unsigned e1 = pl[g][2 * c][1], o1 = pl[g][2 * c + 1][1];
        asm("v_permlane32_swap_b32 %0, %1" : "+v"(e0), "+v"(o0));
        asm("v_permlane16_swap_b32 %0, %1" : "+v"(e0), "+v"(o0));
        asm("v_permlane32_swap_b32 %0, %1" : "+v"(e1), "+v"(o1));
        asm("v_permlane16_swap_b32 %0, %1" : "+v"(e1), "+v"(o1));
        union { unsigned u[4]; bf16x8 v; } uu;
        uu.u[0] = e0; uu.u[1] = e1; uu.u[2] = o0; uu.u[3] = o1;
        pf[g][c] = uu.v;
      }

    // PV: O^T += V^T · P^T ; vf read once, feeds both groups.
    const char* bV = (const char*)&sV[cur][0] + rowb;
    __builtin_amdgcn_s_setprio(1);
#pragma unroll
    for (int ht = 0; ht < 4; ++ht) {
      const bf16x8 vf0 = *(const bf16x8*)(bV + ht * 2048 + koff0);
      const bf16x8 vf1 = *(const bf16x8*)(bV + ht * 2048 + (koff0 ^ 64));
      oacc[0][ht] = __builtin_amdgcn_mfma_f32_16x16x32_bf16(vf0, pf[0][0], oacc[0][ht], 0, 0, 0);
      oacc[0][ht] = __builtin_amdgcn_mfma_f32_16x16x32_bf16(vf1, pf[0][1], oacc[0][ht], 0, 0, 0);
      oacc[1][ht] = __builtin_amdgcn_mfma_f32_16x16x32_bf16(vf0, pf[1][0], oacc[1][ht], 0, 0, 0);
      oacc[1][ht] = __builtin_amdgcn_mfma_f32_16x16x32_bf16(vf1, pf[1][1], oacc[1][ht], 0, 0, 0);
    }
    // l row-sums via ones-MFMA: D[r][q] = sum_k P[k][q] for every r.
    lacc[0] = __builtin_amdgcn_mfma_f32_16x16x32_bf16(onesv, pf[0][0], lacc[0], 0, 0, 0);
    lacc[0] = __builtin_amdgcn_mfma_f32_16x16x32_bf16(onesv, pf[0][1], lacc[0], 0, 0, 0);
    lacc[1] = __builtin_amdgcn_mfma_f32_16x16x32_bf16(onesv, pf[1][0], lacc[1], 0, 0, 0);
    lacc[1] = __builtin_amdgcn_mfma_f32_16x16x32_bf16(onesv, pf[1][1], lacc[1], 0, 0, 0);
    __builtin_amdgcn_s_setprio(0);

    __syncthreads();  // drains DMA (vmcnt) + LDS ops before buffer swap
  }

  // epilogue: every lane holds its q-column's sum in lacc[g][*]
#pragma unroll
  for (int g = 0; g < 2; ++g) {
    const float l = lacc[g][0];
    const float inv = (l > 0.f) ? 1.f / l : 0.f;
    __hip_bfloat16* orow =
        O + (brow + qbase + g * 64 + wave * 16 + l16) * 1024 + h * 64;
#pragma unroll
    for (int ht = 0; ht < 4; ++ht) {
      union { __hip_bfloat16 h[4]; unsigned long long u; } ok_;
#pragma unroll
      for (int r = 0; r < 4; ++r) ok_.h[r] = (__hip_bfloat16)(oacc[g][ht][r] * inv);
      *(unsigned long long*)(orow + ht * 16 + quad * 4) = ok_.u;
    }
  }
}

// ---------------------------------------------------------------------------
extern "C" void kernel_launch(void* const* d_in, const int* in_sizes, int n_in,
                              void* d_out, int out_size, void* d_ws, size_t ws_size,
                              hipStream_t stream) {
  const float* x  = (const float*)d_in[0];
  const int*   mk = (const int*)d_in[1];
  const float* Wq = (const float*)d_in[2];
  const float* bq = (const float*)d_in[3];
  const float* Wk = (const float*)d_in[4];
  const float* bk = (const float*)d_in[5];
  const float* Wv = (const float*)d_in[6];
  const float* bv = (const float*)d_in[7];
  const float* Wo = (const float*)d_in[8];
  const float* bo = (const float*)d_in[9];
  float* out = (float*)d_out;

  __hip_bfloat16* X16    = (__hip_bfloat16*)d_ws;                  // [8192][1024]
  __hip_bfloat16* Wt_qkv = X16 + (size_t)B_ * S_ * D_;             // [3072][1024]
  __hip_bfloat16* Wt_o   = Wt_qkv + (size_t)3 * D_ * D_;           // [1024][1024]
  __hip_bfloat16* QK     = Wt_o + (size_t)D_ * D_;                 // [8192][2048]
  __hip_bfloat16* Vt     = QK + (size_t)B_ * S_ * 2 * D_;          // [4096][2048]
  __hip_bfloat16* Obuf   = Vt + (size_t)B_ * H_ * HD_ * S_;        // [8192][1024]
  unsigned* xmask = (unsigned*)(Obuf + (size_t)B_ * S_ * D_);      // 33.5 MB

  const int nx = B_ * S_ * D_;
  cvt_x<<<dim3((nx / 4 + 255) / 256), 256, 0, stream>>>(x, X16, nx);
  transpose_w<<<dim3(32, 32, 4), dim3(32, 32), 0, stream>>>(Wq, Wk, Wv, Wo, Wt_qkv, Wt_o);
  expand_mask<<<dim3((int)((size_t)B_ * S_ * S_ / 4 / 256)), 256, 0, stream>>>(
      mk, (uint2*)xmask);
  gemm_qkv<<<dim3(24 * 64), 256, 0, stream>>>(
      X16, Wt_qkv, bq, bk, bv, QK, Vt);
  flash_attn<<<dim3(S_ / 128, H_, B_), 256, 0, stream>>>(
      QK, Vt, (const uint4*)xmask, Obuf);
  gemm_out<<<dim3(8 * 64), 256, 0, stream>>>(
      Obuf, Wt_o, bo, out, D_, D_);
}

// Round 7
// 357.790 us; speedup vs baseline: 1.0779x; 1.0067x over previous
//
#include <hip/hip_runtime.h>
#include <hip/hip_bf16.h>
#include <stdint.h>

#define B_  4
#define S_  2048
#define D_  1024
#define H_  16
#define HD_ 64

typedef __attribute__((ext_vector_type(4))) float f32x4;
typedef __attribute__((ext_vector_type(8))) short bf16x8;

typedef const unsigned int __attribute__((address_space(1)))* gas_ptr;
typedef unsigned int __attribute__((address_space(3)))* las_ptr;

__device__ __forceinline__ void async16(const void* g, void* l) {
  __builtin_amdgcn_global_load_lds((gas_ptr)g, (las_ptr)l, 16, 0, 0);
}

// ---------------------------------------------------------------------------
// x fp32 -> bf16
// ---------------------------------------------------------------------------
__global__ __launch_bounds__(256) void cvt_x(const float* __restrict__ in,
                                             __hip_bfloat16* __restrict__ out,
                                             int n) {
  const int i = (blockIdx.x * blockDim.x + threadIdx.x) * 4;
  if (i >= n) return;
  const float4 v = *(const float4*)(in + i);
  union { ushort4 u; __hip_bfloat16 h[4]; } o;
  o.h[0] = (__hip_bfloat16)v.x;
  o.h[1] = (__hip_bfloat16)v.y;
  o.h[2] = (__hip_bfloat16)v.z;
  o.h[3] = (__hip_bfloat16)v.w;
  *(ushort4*)(out + i) = o.u;
}

// ---------------------------------------------------------------------------
// mask int32 -> expanded bf16-AND masks (0xFFFF keep / 0x0000 drop), laid out
// exactly as flash_attn's packed-P pairs consume them:
//   u32 index = ((((b*2048+q)*32 + kt)*4 + quad)*8) + mt*2 + h
// ---------------------------------------------------------------------------
__global__ __launch_bounds__(256) void expand_mask(const int* __restrict__ mk,
                                                   uint2* __restrict__ xm) {
  const unsigned j = blockIdx.x * 256 + threadIdx.x;
  const int mt = j & 3, quad = (j >> 2) & 3, kt = (j >> 4) & 31;
  const int q = (j >> 9) & 2047, b = j >> 20;
  const size_t row = (size_t)b * 2048 + q;
  const int key = kt * 64 + mt * 16 + quad * 4;
  const int4 m = *(const int4*)(mk + row * 2048 + key);
  uint2 o;
  o.x = (m.x ? 0xFFFFu : 0u) | (m.y ? 0xFFFF0000u : 0u);
  o.y = (m.z ? 0xFFFFu : 0u) | (m.w ? 0xFFFF0000u : 0u);
  xm[j] = o;
}

// ---------------------------------------------------------------------------
// weights fp32 [K,N] -> bf16 transposed [N,K]
// ---------------------------------------------------------------------------
__global__ void transpose_w(const float* __restrict__ Wq,
                            const float* __restrict__ Wk,
                            const float* __restrict__ Wv,
                            const float* __restrict__ Wo,
                            __hip_bfloat16* __restrict__ Wt_qkv,
                            __hip_bfloat16* __restrict__ Wt_o) {
  __shared__ float t[32][33];
  const int z = blockIdx.z;
  const float* W = (z == 0) ? Wq : (z == 1) ? Wk : (z == 2) ? Wv : Wo;
  __hip_bfloat16* Wt = (z < 3) ? (Wt_qkv + (size_t)z * D_ * D_) : Wt_o;
  const int x = blockIdx.x * 32 + threadIdx.x;
  const int y = blockIdx.y * 32 + threadIdx.y;
  t[threadIdx.y][threadIdx.x] = W[(size_t)y * D_ + x];
  __syncthreads();
  const int xo = blockIdx.y * 32 + threadIdx.x;
  const int yo = blockIdx.x * 32 + threadIdx.y;
  Wt[(size_t)yo * D_ + xo] = (__hip_bfloat16)t[threadIdx.x][threadIdx.y];
}

// ---------------------------------------------------------------------------
// QKV GEMM, BK=64 + XOR-swizzled LDS (flash-verified algebra): halves the
// barrier count vs BK=32 (16 K-iterations, 32 MFMA per barrier window).
// LDS rows are 128B; DMA lane i covers row (i>>3), physical chunk (i&7)
// sourcing logical chunk (i&7)^(i>>3); reads use ((c*4+quad)^(l16&7))*16
// -> 2 lanes/bank-group (conflict-free). LDS 32KB, <=5 blocks/CU.
// XCD swizzle (T1): nwg=1536, chunk 192/XCD = 8 M-rows.
// ---------------------------------------------------------------------------
__global__ __launch_bounds__(256) void gemm_qkv(
    const __hip_bfloat16* __restrict__ A,
    const __hip_bfloat16* __restrict__ Bt,
    const float* __restrict__ bq,
    const float* __restrict__ bk,
    const float* __restrict__ bv,
    __hip_bfloat16* __restrict__ QKo,
    __hip_bfloat16* __restrict__ Vt) {
  __shared__ __hip_bfloat16 sA[128 * 64];
  __shared__ __hip_bfloat16 sB[128 * 64];
  const int K = 1024;
  const int tid  = threadIdx.x;
  const int wave = tid >> 6;
  const int lane = tid & 63;
  const int quad = lane >> 4;
  const int l16  = lane & 15;
  const int wg  = blockIdx.x;
  const int swz = (wg & 7) * 192 + (wg >> 3);
  const int bm = (swz / 24) * 128;
  const int bn = (swz % 24) * 128;
  const int wm = (wave >> 1) * 64;
  const int wn = (wave & 1) * 64;

  // DMA staging (BK=64): wave covers rows wave*32 .. wave*32+31 in 4 instr.
  const int srow = lane >> 3;
  const int schk = (lane & 7) ^ srow;
  const __hip_bfloat16* gA = A  + (size_t)(bm + wave * 32 + srow) * K + schk * 8;
  const __hip_bfloat16* gB = Bt + (size_t)(bn + wave * 32 + srow) * K + schk * 8;
  char* const lA = (char*)sA + wave * 32 * 128;
  char* const lB = (char*)sB + wave * 32 * 128;

  // fragment-read swizzle: logical chunk c*4+quad, row parity l16&7
  const int xl = l16 & 7;
  const int koff = (quad ^ xl) * 16;          // c=0; c=1 => ^64
  const char* pa = (const char*)sA + (wm + l16) * 128;
  const char* pb = (const char*)sB + (wn + l16) * 128;

  f32x4 acc[4][4] = {};

  for (int k0 = 0; k0 < K; k0 += 64) {
#pragma unroll
    for (int t = 0; t < 4; ++t) {
      async16(gA + (size_t)(t * 8) * K + k0, lA + t * 1024);
      async16(gB + (size_t)(t * 8) * K + k0, lB + t * 1024);
    }
    __syncthreads();
#pragma unroll
    for (int c = 0; c < 2; ++c) {
      const int off = koff ^ (c * 64);
      bf16x8 af[4], bf[4];
#pragma unroll
      for (int mt = 0; mt < 4; ++mt) af[mt] = *(const bf16x8*)(pa + mt * 2048 + off);
#pragma unroll
      for (int nt = 0; nt < 4; ++nt) bf[nt] = *(const bf16x8*)(pb + nt * 2048 + off);
#pragma unroll
      for (int mt = 0; mt < 4; ++mt)
#pragma unroll
        for (int nt = 0; nt < 4; ++nt)
          acc[mt][nt] = __builtin_amdgcn_mfma_f32_16x16x32_bf16(af[mt], bf[nt], acc[mt][nt], 0, 0, 0);
    }
    __syncthreads();
  }

#pragma unroll
  for (int mt = 0; mt < 4; ++mt) {
    const int row = bm + wm + mt * 16 + quad * 4;
#pragma unroll
    for (int nt = 0; nt < 4; ++nt) {
      const int col = bn + wn + nt * 16 + l16;
      f32x4 v = acc[mt][nt];
      if (col < 2048) {
        const float bias = (col < 1024) ? bq[col] : bk[col - 1024];
        const float sc = (col < 1024) ? 0.18033688011f : 1.0f;  // 0.125*log2(e)
#pragma unroll
        for (int r = 0; r < 4; ++r)
          QKo[(size_t)(row + r) * 2048 + col] = (__hip_bfloat16)((v[r] + bias) * sc);
      } else {
        const int cv = col - 2048;
        const float bias = bv[cv];
        const int hh = cv >> 6, d = cv & 63;
        const int bb = row >> 11, s0 = row & 2047;
        union { __hip_bfloat16 h[4]; unsigned long long u; } pk;
#pragma unroll
        for (int r = 0; r < 4; ++r) pk.h[r] = (__hip_bfloat16)(v[r] + bias);
        *(unsigned long long*)(Vt + ((size_t)(bb * 16 + hh) * 64 + d) * 2048 + s0) = pk.u;
      }
    }
  }
}

// ---------------------------------------------------------------------------
// Out-proj GEMM, same BK=64 swizzled structure, fp32 output.
// XCD swizzle: nwg=512, chunk 64/XCD = 8 M-rows.
// ---------------------------------------------------------------------------
__global__ __launch_bounds__(256) void gemm_out(
    const __hip_bfloat16* __restrict__ A,
    const __hip_bfloat16* __restrict__ Bt,
    const float* __restrict__ b0,
    float* __restrict__ C,
    int N, int K) {
  __shared__ __hip_bfloat16 sA[128 * 64];
  __shared__ __hip_bfloat16 sB[128 * 64];
  const int tid  = threadIdx.x;
  const int wave = tid >> 6;
  const int lane = tid & 63;
  const int quad = lane >> 4;
  const int l16  = lane & 15;
  const int wg  = blockIdx.x;
  const int swz = (wg & 7) * 64 + (wg >> 3);
  const int bm = (swz >> 3) * 128;
  const int bn = (swz & 7) * 128;
  const int wm = (wave >> 1) * 64;
  const int wn = (wave & 1) * 64;

  const int srow = lane >> 3;
  const int schk = (lane & 7) ^ srow;
  const __hip_bfloat16* gA = A  + (size_t)(bm + wave * 32 + srow) * K + schk * 8;
  const __hip_bfloat16* gB = Bt + (size_t)(bn + wave * 32 + srow) * K + schk * 8;
  char* const lA = (char*)sA + wave * 32 * 128;
  char* const lB = (char*)sB + wave * 32 * 128;

  const int xl = l16 & 7;
  const int koff = (quad ^ xl) * 16;
  const char* pa = (const char*)sA + (wm + l16) * 128;
  const char* pb = (const char*)sB + (wn + l16) * 128;

  f32x4 acc[4][4] = {};

  for (int k0 = 0; k0 < K; k0 += 64) {
#pragma unroll
    for (int t = 0; t < 4; ++t) {
      async16(gA + (size_t)(t * 8) * K + k0, lA + t * 1024);
      async16(gB + (size_t)(t * 8) * K + k0, lB + t * 1024);
    }
    __syncthreads();
#pragma unroll
    for (int c = 0; c < 2; ++c) {
      const int off = koff ^ (c * 64);
      bf16x8 af[4], bf[4];
#pragma unroll
      for (int mt = 0; mt < 4; ++mt) af[mt] = *(const bf16x8*)(pa + mt * 2048 + off);
#pragma unroll
      for (int nt = 0; nt < 4; ++nt) bf[nt] = *(const bf16x8*)(pb + nt * 2048 + off);
#pragma unroll
      for (int mt = 0; mt < 4; ++mt)
#pragma unroll
        for (int nt = 0; nt < 4; ++nt)
          acc[mt][nt] = __builtin_amdgcn_mfma_f32_16x16x32_bf16(af[mt], bf[nt], acc[mt][nt], 0, 0, 0);
    }
    __syncthreads();
  }

#pragma unroll
  for (int mt = 0; mt < 4; ++mt) {
    const int row = bm + wm + mt * 16 + quad * 4;
#pragma unroll
    for (int nt = 0; nt < 4; ++nt) {
      const int col = bn + wn + nt * 16 + l16;
      const float bias = b0[col];
      f32x4 v = acc[mt][nt];
#pragma unroll
      for (int r = 0; r < 4; ++r)
        C[(size_t)(row + r) * N + col] = v[r] + bias;
    }
  }
}

// ---------------------------------------------------------------------------
// Flash attention v9 (proven local optimum of the 2-barrier structure).
// ---------------------------------------------------------------------------
__global__ __launch_bounds__(256, 4) void flash_attn(
    const __hip_bfloat16* __restrict__ QK,            // [8192][2048]
    const __hip_bfloat16* __restrict__ Vt,            // [B*H*64][2048]
    const uint4* __restrict__ XM,                     // expanded masks
    __hip_bfloat16* __restrict__ O) {                 // [8192][1024]
  __shared__ __hip_bfloat16 sK[2][64 * 64];
  __shared__ __hip_bfloat16 sV[2][64 * 64];

  const int qt = blockIdx.x, h = blockIdx.y, b = blockIdx.z;
  const int tid = threadIdx.x;
  const int wave = tid >> 6, lane = tid & 63, quad = lane >> 4, l16 = lane & 15;
  const int qbase = qt * 128;
  const size_t brow = (size_t)b * S_;
  const int bh = b * H_ + h;

  // Q fragments direct from global: B-operand, lane n = l16 = q row.
  bf16x8 qf[2][2];
#pragma unroll
  for (int g = 0; g < 2; ++g) {
    const __hip_bfloat16* qrow =
        QK + (brow + qbase + g * 64 + wave * 16 + l16) * 2048 + h * 64;
#pragma unroll
    for (int c = 0; c < 2; ++c)
      qf[g][c] = *(const bf16x8*)(qrow + c * 32 + quad * 8);
  }

  // DMA staging: lane i of instr t covers row wave*16 + t*8 + (i>>3),
  // physical chunk i&7 = logical chunk (i&7)^(i>>3) (XOR swizzle).
  const int srow = lane >> 3;
  const int schk = (lane & 7) ^ srow;
  const __hip_bfloat16* gk0 =
      QK + (brow + wave * 16 + srow) * 2048 + 1024 + h * 64 + schk * 8;
  const __hip_bfloat16* gk1 = gk0 + (size_t)8 * 2048;
  const __hip_bfloat16* gv0 =
      Vt + ((size_t)bh * 64 + wave * 16 + srow) * 2048 + schk * 8;
  const __hip_bfloat16* gv1 = gv0 + (size_t)8 * 2048;
  char* const lK[2] = {(char*)&sK[0][0] + wave * 2048, (char*)&sK[1][0] + wave * 2048};
  char* const lV[2] = {(char*)&sV[0][0] + wave * 2048, (char*)&sV[1][0] + wave * 2048};

  // expanded-mask pointers: per q-row 256 uint4; per kt 8; per quad 2.
  const uint4* xpa = XM + ((brow + qbase + wave * 16 + l16) * 256 + quad * 2);
  const uint4* xpb = xpa + (size_t)64 * 256;

  // fragment-read swizzle offsets (chunk c*4+quad, row parity l16&7)
  const int xl = l16 & 7;
  const int koff0 = ((quad ^ xl) * 16);        // c=0 chunk; c=1 = koff0^64
  const int rowb = l16 * 128;

  const bf16x8 onesv = {(short)0x3F80, (short)0x3F80, (short)0x3F80, (short)0x3F80,
                        (short)0x3F80, (short)0x3F80, (short)0x3F80, (short)0x3F80};
  f32x4 lacc[2] = {};
  f32x4 oacc[2][4] = {};

  // prologue: stage tile 0, prefetch tile-0 mask words
  async16(gk0, lK[0]);
  async16(gk1, lK[0] + 1024);
  async16(gv0, lV[0]);
  async16(gv1, lV[0] + 1024);
  uint4 x0a = xpa[0], x1a = xpa[1], x0b = xpb[0], x1b = xpb[1];
  gk0 += (size_t)64 * 2048; gk1 += (size_t)64 * 2048;
  gv0 += 64; gv1 += 64;
  __syncthreads();

  const int NT = S_ / 64;
  for (int kt = 0; kt < NT; ++kt) {
    const int cur = kt & 1, nxt = cur ^ 1;

    // issue next tile's DMA (overlaps this tile's compute; disjoint buffer)
    if (kt + 1 < NT) {
      async16(gk0, lK[nxt]);
      async16(gk1, lK[nxt] + 1024);
      async16(gv0, lV[nxt]);
      async16(gv1, lV[nxt] + 1024);
      gk0 += (size_t)64 * 2048; gk1 += (size_t)64 * 2048;
      gv0 += 64; gv1 += 64;
    }
    const uint4 ca0 = x0a, ca1 = x1a, cb0 = x0b, cb1 = x1b;
    const int kn = (kt + 1 < NT) ? kt + 1 : kt;
    x0a = xpa[kn * 8]; x1a = xpa[kn * 8 + 1];
    x0b = xpb[kn * 8]; x1b = xpb[kn * 8 + 1];

    // QK with fused exp/pack/AND-mask: kf read once feeds both q-groups.
    const char* bK = (const char*)&sK[cur][0] + rowb;
    unsigned pl[2][4][2];
#pragma unroll
    for (int mt = 0; mt < 4; ++mt) {
      const bf16x8 kf0 = *(const bf16x8*)(bK + mt * 2048 + koff0);
      const bf16x8 kf1 = *(const bf16x8*)(bK + mt * 2048 + (koff0 ^ 64));
      f32x4 a0 = {}, a1 = {};
      __builtin_amdgcn_s_setprio(1);
      a0 = __builtin_amdgcn_mfma_f32_16x16x32_bf16(kf0, qf[0][0], a0, 0, 0, 0);
      a0 = __builtin_amdgcn_mfma_f32_16x16x32_bf16(kf1, qf[0][1], a0, 0, 0, 0);
      a1 = __builtin_amdgcn_mfma_f32_16x16x32_bf16(kf0, qf[1][0], a1, 0, 0, 0);
      a1 = __builtin_amdgcn_mfma_f32_16x16x32_bf16(kf1, qf[1][1], a1, 0, 0, 0);
      __builtin_amdgcn_s_setprio(0);
#pragma unroll
      for (int g = 0; g < 2; ++g) {
        const uint4 cc = g ? ((mt < 2) ? cb0 : cb1) : ((mt < 2) ? ca0 : ca1);
        const unsigned w0 = (mt & 1) ? cc.z : cc.x;
        const unsigned w1 = (mt & 1) ? cc.w : cc.y;
        const f32x4 av = g ? a1 : a0;
        union { __hip_bfloat16 h[2]; unsigned u; } c0, c1;
        c0.h[0] = (__hip_bfloat16)__builtin_amdgcn_exp2f(av[0]);
        c0.h[1] = (__hip_bfloat16)__builtin_amdgcn_exp2f(av[1]);
        c1.h[0] = (__hip_bfloat16)__builtin_amdgcn_exp2f(av[2]);
        c1.h[1] = (__hip_bfloat16)__builtin_amdgcn_exp2f(av[3]);
        pl[g][mt][0] = c0.u & w0;
        pl[g][mt][1] = c1.u & w1;
      }
    }

    // In-register P^T -> B-operand redistribution (permlane swaps).
    // VDST = even-mt word (E), SRC0 = odd-mt word (O); after the two swaps
    // E = pf words {0,1}, O = pf words {2,3}.
    bf16x8 pf[2][2];
#pragma unroll
    for (int g = 0; g < 2; ++g)
#pragma unroll
      for (int c = 0; c < 2; ++c) {
        unsigned e0 = pl[g][2 * c][0], o0 = pl[g][2 * c + 1][0];
        unsigned e1 = pl[g][2 * c][1], o1 = pl[g][2 * c + 1][1];
        asm("v_permlane32_swap_b32 %0, %1" : "+v"(e0), "+v"(o0));
        asm("v_permlane16_swap_b32 %0, %1" : "+v"(e0), "+v"(o0));
        asm("v_permlane32_swap_b32 %0, %1" : "+v"(e1), "+v"(o1));
        asm("v_permlane16_swap_b32 %0, %1" : "+v"(e1), "+v"(o1));
        union { unsigned u[4]; bf16x8 v; } uu;
        uu.u[0] = e0; uu.u[1] = e1; uu.u[2] = o0; uu.u[3] = o1;
        pf[g][c] = uu.v;
      }

    // PV: O^T += V^T · P^T ; vf read once, feeds both groups.
    const char* bV = (const char*)&sV[cur][0] + rowb;
    __builtin_amdgcn_s_setprio(1);
#pragma unroll
    for (int ht = 0; ht < 4; ++ht) {
      const bf16x8 vf0 = *(const bf16x8*)(bV + ht * 2048 + koff0);
      const bf16x8 vf1 = *(const bf16x8*)(bV + ht * 2048 + (koff0 ^ 64));
      oacc[0][ht] = __builtin_amdgcn_mfma_f32_16x16x32_bf16(vf0, pf[0][0], oacc[0][ht], 0, 0, 0);
      oacc[0][ht] = __builtin_amdgcn_mfma_f32_16x16x32_bf16(vf1, pf[0][1], oacc[0][ht], 0, 0, 0);
      oacc[1][ht] = __builtin_amdgcn_mfma_f32_16x16x32_bf16(vf0, pf[1][0], oacc[1][ht], 0, 0, 0);
      oacc[1][ht] = __builtin_amdgcn_mfma_f32_16x16x32_bf16(vf1, pf[1][1], oacc[1][ht], 0, 0, 0);
    }
    // l row-sums via ones-MFMA: D[r][q] = sum_k P[k][q] for every r.
    lacc[0] = __builtin_amdgcn_mfma_f32_16x16x32_bf16(onesv, pf[0][0], lacc[0], 0, 0, 0);
    lacc[0] = __builtin_amdgcn_mfma_f32_16x16x32_bf16(onesv, pf[0][1], lacc[0], 0, 0, 0);
    lacc[1] = __builtin_amdgcn_mfma_f32_16x16x32_bf16(onesv, pf[1][0], lacc[1], 0, 0, 0);
    lacc[1] = __builtin_amdgcn_mfma_f32_16x16x32_bf16(onesv, pf[1][1], lacc[1], 0, 0, 0);
    __builtin_amdgcn_s_setprio(0);

    __syncthreads();  // drains DMA (vmcnt) + LDS ops before buffer swap
  }

  // epilogue: every lane holds its q-column's sum in lacc[g][*]
#pragma unroll
  for (int g = 0; g < 2; ++g) {
    const float l = lacc[g][0];
    const float inv = (l > 0.f) ? 1.f / l : 0.f;
    __hip_bfloat16* orow =
        O + (brow + qbase + g * 64 + wave * 16 + l16) * 1024 + h * 64;
#pragma unroll
    for (int ht = 0; ht < 4; ++ht) {
      union { __hip_bfloat16 h[4]; unsigned long long u; } ok_;
#pragma unroll
      for (int r = 0; r < 4; ++r) ok_.h[r] = (__hip_bfloat16)(oacc[g][ht][r] * inv);
      *(unsigned long long*)(orow + ht * 16 + quad * 4) = ok_.u;
    }
  }
}

// ---------------------------------------------------------------------------
extern "C" void kernel_launch(void* const* d_in, const int* in_sizes, int n_in,
                              void* d_out, int out_size, void* d_ws, size_t ws_size,
                              hipStream_t stream) {
  const float* x  = (const float*)d_in[0];
  const int*   mk = (const int*)d_in[1];
  const float* Wq = (const float*)d_in[2];
  const float* bq = (const float*)d_in[3];
  const float* Wk = (const float*)d_in[4];
  const float* bk = (const float*)d_in[5];
  const float* Wv = (const float*)d_in[6];
  const float* bv = (const float*)d_in[7];
  const float* Wo = (const float*)d_in[8];
  const float* bo = (const float*)d_in[9];
  float* out = (float*)d_out;

  __hip_bfloat16* X16    = (__hip_bfloat16*)d_ws;                  // [8192][1024]
  __hip_bfloat16* Wt_qkv = X16 + (size_t)B_ * S_ * D_;             // [3072][1024]
  __hip_bfloat16* Wt_o   = Wt_qkv + (size_t)3 * D_ * D_;           // [1024][1024]
  __hip_bfloat16* QK     = Wt_o + (size_t)D_ * D_;                 // [8192][2048]
  __hip_bfloat16* Vt     = QK + (size_t)B_ * S_ * 2 * D_;          // [4096][2048]
  __hip_bfloat16* Obuf   = Vt + (size_t)B_ * H_ * HD_ * S_;        // [8192][1024]
  unsigned* xmask = (unsigned*)(Obuf + (size_t)B_ * S_ * D_);      // 33.5 MB

  const int nx = B_ * S_ * D_;
  cvt_x<<<dim3((nx / 4 + 255) / 256), 256, 0, stream>>>(x, X16, nx);
  transpose_w<<<dim3(32, 32, 4), dim3(32, 32), 0, stream>>>(Wq, Wk, Wv, Wo, Wt_qkv, Wt_o);
  expand_mask<<<dim3((int)((size_t)B_ * S_ * S_ / 4 / 256)), 256, 0, stream>>>(
      mk, (uint2*)xmask);
  gemm_qkv<<<dim3(24 * 64), 256, 0, stream>>>(
      X16, Wt_qkv, bq, bk, bv, QK, Vt);
  flash_attn<<<dim3(S_ / 128, H_, B_), 256, 0, stream>>>(
      QK, Vt, (const uint4*)xmask, Obuf);
  gemm_out<<<dim3(8 * 64), 256, 0, stream>>>(
      Obuf, Wt_o, bo, out, D_, D_);
}